// Round 1
// baseline (51575.995 us; speedup 1.0000x reference)
//
#include <hip/hip_runtime.h>
#include <stdint.h>

#define NTHR 256
#define NBLKS 256

namespace cfg {
// ws layout in FLOAT units (cells region counted in floats too; they're u32)
constexpr size_t F_CELLS = 0;                    // 32768 u32 barrier cells (stride 32)
constexpr size_t F_H0    = 32768;                // [32][512]
constexpr size_t F_C0    = F_H0 + 16384;
constexpr size_t F_H1    = F_C0 + 16384;
constexpr size_t F_C1    = F_H1 + 16384;
constexpr size_t F_APART = F_C1 + 16384;         // [2][8][32][512] attn partials (parity dbuf)
constexpr size_t F_VN    = F_APART + 262144;     // [512] normalized v
constexpr size_t F_CTX   = F_VN + 512;           // [32][1024]
constexpr size_t F_P0    = F_CTX + 32768;        // [8][32][2048] gates0 / enc-fw partials
constexpr size_t F_P1    = F_P0 + 524288;        // [8][32][2048] gates1 / enc-bw partials
constexpr size_t F_PLO   = F_P1 + 524288;        // [32][9000] projection low-K partial
constexpr size_t F_EOUT  = F_PLO + 288000;       // [32][128][1024] encoder output
constexpr size_t F_KEYS  = F_EOUT + 4194304;     // [32][128][512]
constexpr size_t F_TOTAL = F_KEYS + 2097152;     // ~32.1 MB
constexpr size_t MEMSET_BYTES = F_VN * 4;        // cells + states + attn partials
}

__device__ __forceinline__ float sigm(float x)   { return 1.0f / (1.0f + __expf(-x)); }
__device__ __forceinline__ float tanhft(float x) { return 1.0f - 2.0f / (1.0f + __expf(2.0f * x)); }

// device-scope grid barrier: single-use counter cell per barrier (memset to 0 each call)
__device__ __forceinline__ void gbar(unsigned* cell) {
  __syncthreads();
  if (threadIdx.x == 0) {
    __threadfence();  // make this block's global writes visible device-wide
    __hip_atomic_fetch_add(cell, 1u, __ATOMIC_ACQ_REL, __HIP_MEMORY_SCOPE_AGENT);
    while (__hip_atomic_load(cell, __ATOMIC_RELAXED, __HIP_MEMORY_SCOPE_AGENT) < gridDim.x) {
      __builtin_amdgcn_s_sleep(2);
    }
    __threadfence();  // acquire: invalidate caches before reading others' data
  }
  __syncthreads();
}

// stage A-tile [32][KWIN] into LDS, fully coalesced in k
template<int KWIN, typename F>
__device__ __forceinline__ void stage(float* at, F&& f) {
  __syncthreads();
  constexpr int TOT = 32 * KWIN;
  for (int i = threadIdx.x; i < TOT; i += NTHR) {
    int m = i / KWIN;
    int kl = i - m * KWIN;
    at[i] = f(m, kl);
  }
  __syncthreads();
}

// each wave: 64 consecutive n-cols (lane=n), all 32 m rows, K-chunk KWIN/4.
// leaves 4 wave-partials in red[4][32][64]; ends with __syncthreads.
template<int KWIN>
__device__ __forceinline__ void gemm_acc(const float* __restrict__ W, int ldw,
                                         int n0, int nlim, int kw0,
                                         const float* at, float* red) {
  const int wave = threadIdx.x >> 6, lane = threadIdx.x & 63;
  constexpr int KQ = KWIN / 4;
  const int klo = wave * KQ;
  const int n = n0 + lane;
  const bool nok = n < nlim;
  const float* wp = W + (size_t)(kw0 + klo) * (size_t)ldw + n;
  float acc[32];
#pragma unroll
  for (int m = 0; m < 32; m++) acc[m] = 0.f;
#pragma unroll 1
  for (int kk = 0; kk < KQ; kk += 4) {
    float w0 = 0.f, w1 = 0.f, w2 = 0.f, w3 = 0.f;
    if (nok) {
      w0 = wp[0];
      w1 = wp[(size_t)ldw];
      w2 = wp[(size_t)2 * ldw];
      w3 = wp[(size_t)3 * ldw];
    }
    wp += (size_t)4 * ldw;
    const float* ap = at + klo + kk;
#pragma unroll
    for (int m = 0; m < 32; m++) {
      float4 a = *(const float4*)(ap + m * KWIN);  // LDS broadcast (same addr all lanes)
      acc[m] = fmaf(a.x, w0, acc[m]);
      acc[m] = fmaf(a.y, w1, acc[m]);
      acc[m] = fmaf(a.z, w2, acc[m]);
      acc[m] = fmaf(a.w, w3, acc[m]);
    }
  }
#pragma unroll
  for (int m = 0; m < 32; m++) red[(wave * 32 + m) * 64 + lane] = acc[m];
  __syncthreads();
}

__device__ __forceinline__ void epi_to(const float* red, float* outp, int ldo, int n0, int nlim) {
  for (int i = threadIdx.x; i < 2048; i += NTHR) {
    int m = i >> 6, nn = i & 63;
    int n = n0 + nn;
    if (n < nlim) {
      float s = red[m * 64 + nn] + red[2048 + m * 64 + nn] +
                red[4096 + m * 64 + nn] + red[6144 + m * 64 + nn];
      outp[(size_t)m * ldo + n] = s;
    }
  }
}

__global__ __launch_bounds__(NTHR, 2) void seq2seq_kernel(
    const float* __restrict__ embed_in, const float* __restrict__ dec_embed,
    const int* __restrict__ lens,
    const float* __restrict__ Wfw, const float* __restrict__ bfw,
    const float* __restrict__ Wbw, const float* __restrict__ bbw,
    const float* __restrict__ Wd0, const float* __restrict__ bd0,
    const float* __restrict__ Wd1, const float* __restrict__ bd1,
    const float* __restrict__ Wmem, const float* __restrict__ Wq,
    const float* __restrict__ battn, const float* __restrict__ vattn,
    const float* __restrict__ gattn, const float* __restrict__ Wal,
    const float* __restrict__ Wproj, const float* __restrict__ bproj,
    float* __restrict__ out, float* ws) {
  __shared__ float smem[16384];  // 64 KiB: at = [0,8192), red = [8192,16384)
  float* at  = smem;
  float* red = smem + 8192;

  unsigned* cells = (unsigned*)ws;
  float* h0    = ws + cfg::F_H0;
  float* c0    = ws + cfg::F_C0;
  float* h1    = ws + cfg::F_H1;
  float* c1    = ws + cfg::F_C1;
  float* apart = ws + cfg::F_APART;  // [2][8][32][512], parity stride 131072
  float* vn    = ws + cfg::F_VN;
  float* ctx   = ws + cfg::F_CTX;
  float* p0    = ws + cfg::F_P0;
  float* p1    = ws + cfg::F_P1;
  float* plo   = ws + cfg::F_PLO;
  float* eout  = ws + cfg::F_EOUT;
  float* keysp = ws + cfg::F_KEYS;

  const int bid = blockIdx.x, tid = threadIdx.x;
  const int wave = tid >> 6, lane = tid & 63;
  unsigned* cellp = cells;
#define BAR() do { gbar(cellp); cellp += 32; } while (0)

  // ---------------- setup: normalized attention vector ----------------
  if (bid == 0) {
    float s = 0.f;
    for (int u = tid; u < 512; u += NTHR) { float x = vattn[u]; s = fmaf(x, x, s); }
#pragma unroll
    for (int off = 32; off > 0; off >>= 1) s += __shfl_xor(s, off, 64);
    if (lane == 0) at[64 + wave] = s;
    __syncthreads();
    float S = at[64] + at[65] + at[66] + at[67];
    float scale = gattn[0] / sqrtf(S);
    for (int u = tid; u < 512; u += NTHR) vn[u] = vattn[u] * scale;
  }
  BAR();

  // ---------------- bidirectional encoder ----------------
  // states: h0/c0 = fw, h1/c1 = bw (these ARE the decoder init states)
  for (int t = 0; t < 128; t++) {
    // phase A: fw+bw gate GEMMs, K = 512(x) + 512(h), split: 2dir x 32nb x 4kb
    {
      int dir = bid >> 7;
      int r = bid & 127;
      int nb = r & 31, kb = r >> 5;
      const float* W = dir ? Wbw : Wfw;
      const float* hs = dir ? h1 : h0;
      stage<256>(at, [&](int m, int kl) -> float {
        int kk = kb * 256 + kl;
        if (kk < 512) {
          int tt = t;
          if (dir) { int len = lens[m]; tt = (t < len) ? (len - 1 - t) : t; }
          return embed_in[((size_t)m * 128 + tt) * 512 + kk];
        }
        return hs[m * 512 + kk - 512];
      });
      gemm_acc<256>(W, 2048, nb * 64, 2048, kb * 256, at, red);
      epi_to(red, (dir ? p1 : p0) + kb * 65536, 2048, nb * 64, 2048);
    }
    BAR();
    // phase B: activations + masked state update + enc_out write
    if (bid < 128) {
      int dir = bid >> 6;
      int p = (bid & 63) * NTHR + tid;  // 0..16383
      int m = p >> 9, u = p & 511;
      const float* parts = dir ? p1 : p0;
      const float* bias  = dir ? bbw : bfw;
      float* hs = dir ? h1 : h0;
      float* cs = dir ? c1 : c0;
      float g4[4];
#pragma unroll
      for (int g = 0; g < 4; g++) {
        float s = bias[g * 512 + u];
#pragma unroll
        for (int j = 0; j < 4; j++) s += parts[j * 65536 + m * 2048 + g * 512 + u];
        g4[g] = s;
      }
      int len = lens[m];
      bool valid = t < len;
      float co = cs[m * 512 + u];
      float cn = sigm(g4[2] + 1.f) * co + sigm(g4[0]) * tanhft(g4[1]);
      float hn = sigm(g4[3]) * tanhft(cn);
      if (valid) { cs[m * 512 + u] = cn; hs[m * 512 + u] = hn; }
      int tpos = dir ? (valid ? (len - 1 - t) : t) : t;
      eout[((size_t)m * 128 + tpos) * 1024 + dir * 512 + u] = valid ? hn : 0.f;
    }
    BAR();
  }

  // ---------------- keys = enc_out @ w_mem  (M=4096, N=512, K=1024) ----------------
  {
#pragma unroll 1
    for (int task = bid; task < 1024; task += NBLKS) {
      int mt = task >> 3, nb = task & 7;
      int n0 = nb * 64;
      const float* arow = eout + (size_t)mt * 32 * 1024;
      float acc[32];
#pragma unroll
      for (int m = 0; m < 32; m++) acc[m] = 0.f;
      const int n = n0 + lane;
#pragma unroll 1
      for (int c = 0; c < 4; c++) {
        stage<256>(at, [&](int m, int kl) -> float {
          return arow[(size_t)m * 1024 + c * 256 + kl];
        });
        const int klo = wave * 64;
        const float* wp = Wmem + (size_t)(c * 256 + klo) * 512 + n;
#pragma unroll 1
        for (int kk = 0; kk < 64; kk += 4) {
          float w0 = wp[0], w1 = wp[512], w2 = wp[1024], w3 = wp[1536];
          wp += 2048;
          const float* ap = at + klo + kk;
#pragma unroll
          for (int m = 0; m < 32; m++) {
            float4 a = *(const float4*)(ap + m * 256);
            acc[m] = fmaf(a.x, w0, acc[m]); acc[m] = fmaf(a.y, w1, acc[m]);
            acc[m] = fmaf(a.z, w2, acc[m]); acc[m] = fmaf(a.w, w3, acc[m]);
          }
        }
      }
      __syncthreads();
#pragma unroll
      for (int m = 0; m < 32; m++) red[(wave * 32 + m) * 64 + lane] = acc[m];
      __syncthreads();
      epi_to(red, keysp + (size_t)mt * 32 * 512, 512, n0, 512);
    }
  }
  BAR();

  // ---------------- decoder loop (t==128 runs only the trailing projection) ----------------
  for (int t = 0; t <= 128; t++) {
    if (t < 128) {
      // phase A: gates0 GEMM, K=1536 = x(512) | attn(512, 8-partial sum) | h0(512)
      {
        int nb = bid & 31, kb = bid >> 5;
        const float* apar = apart + (size_t)((t & 1) ^ 1) * 131072;
        stage<192>(at, [&](int m, int kl) -> float {
          int kk = kb * 192 + kl;
          if (kk < 512) return dec_embed[((size_t)m * 128 + t) * 512 + kk];
          if (kk < 1024) {
            int u = kk - 512;
            float s = 0.f;
#pragma unroll
            for (int j = 0; j < 8; j++) s += apar[j * 16384 + m * 512 + u];
            return s;
          }
          return h0[m * 512 + kk - 1024];
        });
        gemm_acc<192>(Wd0, 2048, nb * 64, 2048, kb * 192, at, red);
        epi_to(red, p0 + kb * 65536, 2048, nb * 64, 2048);
      }
      BAR();
      // phase B: act0 -> h0,c0 (unconditional)
      if (bid < 64) {
        int p = bid * NTHR + tid;
        int m = p >> 9, u = p & 511;
        float g4[4];
#pragma unroll
        for (int g = 0; g < 4; g++) {
          float s = bd0[g * 512 + u];
#pragma unroll
          for (int j = 0; j < 8; j++) s += p0[j * 65536 + m * 2048 + g * 512 + u];
          g4[g] = s;
        }
        float co = c0[m * 512 + u];
        float cn = sigm(g4[2] + 1.f) * co + sigm(g4[0]) * tanhft(g4[1]);
        float hn = sigm(g4[3]) * tanhft(cn);
        c0[m * 512 + u] = cn;
        h0[m * 512 + u] = hn;
      }
      BAR();
      // phase C: gates1 GEMM, K=1024 = h0n(512) | h1_old(512)
      {
        int nb = bid & 31, kb = bid >> 5;
        stage<128>(at, [&](int m, int kl) -> float {
          int kk = kb * 128 + kl;
          return (kk < 512) ? h0[m * 512 + kk] : h1[m * 512 + kk - 512];
        });
        gemm_acc<128>(Wd1, 2048, nb * 64, 2048, kb * 128, at, red);
        epi_to(red, p1 + kb * 65536, 2048, nb * 64, 2048);
      }
      BAR();
    }

    // phase E: attention per batch row (blocks 0..31) || projection-lo(t-1) (blocks 32..172)
    if (t < 128 && bid < 32) {
      int b = bid;
      int len = lens[b];
      float* sh_h1v = at;          // 512
      float* sh_qb  = at + 512;    // 512
      float* sh_vnv = at + 1024;   // 512
      float* sh_sc  = at + 1536;   // 128
      float* sh_al  = at + 1664;   // 128
      float* sh_r   = at + 1792;   // 16
      float* redq   = at + 2048;   // 2048
      // act1 (this block is the sole writer for row b) + stage vn
#pragma unroll 1
      for (int u = tid; u < 512; u += NTHR) {
        float g4[4];
#pragma unroll
        for (int g = 0; g < 4; g++) {
          float s = bd1[g * 512 + u];
#pragma unroll
          for (int j = 0; j < 8; j++) s += p1[j * 65536 + b * 2048 + g * 512 + u];
          g4[g] = s;
        }
        float co = c1[b * 512 + u];
        float cn = sigm(g4[2] + 1.f) * co + sigm(g4[0]) * tanhft(g4[1]);
        float hn = sigm(g4[3]) * tanhft(cn);
        c1[b * 512 + u] = cn;
        h1[b * 512 + u] = hn;
        sh_h1v[u] = hn;
        sh_vnv[u] = vn[u];
      }
      __syncthreads();
      // q = h1n @ w_query  (waves split K, lanes cover u)
      {
        float4 qa = make_float4(0.f, 0.f, 0.f, 0.f), qb4 = make_float4(0.f, 0.f, 0.f, 0.f);
        const int ua = lane * 4, ub = 256 + lane * 4;
        const float* wqp = Wq + (size_t)(wave * 128) * 512;
#pragma unroll 1
        for (int kk = 0; kk < 128; kk++) {
          float h = sh_h1v[wave * 128 + kk];
          float4 wa = *(const float4*)(wqp + (size_t)kk * 512 + ua);
          float4 wb = *(const float4*)(wqp + (size_t)kk * 512 + ub);
          qa.x = fmaf(h, wa.x, qa.x); qa.y = fmaf(h, wa.y, qa.y);
          qa.z = fmaf(h, wa.z, qa.z); qa.w = fmaf(h, wa.w, qa.w);
          qb4.x = fmaf(h, wb.x, qb4.x); qb4.y = fmaf(h, wb.y, qb4.y);
          qb4.z = fmaf(h, wb.z, qb4.z); qb4.w = fmaf(h, wb.w, qb4.w);
        }
        *(float4*)(redq + wave * 512 + ua) = qa;
        *(float4*)(redq + wave * 512 + ub) = qb4;
      }
      __syncthreads();
      for (int u = tid; u < 512; u += NTHR)
        sh_qb[u] = redq[u] + redq[512 + u] + redq[1024 + u] + redq[1536 + u] + battn[u];
      __syncthreads();
      // scores
#pragma unroll 1
      for (int tt = 0; tt < 32; tt++) {
        int tq = wave * 32 + tt;
        const float* kp = keysp + ((size_t)b * 128 + tq) * 512;
        float s = 0.f;
#pragma unroll
        for (int hh = 0; hh < 2; hh++) {
          int u = lane * 4 + hh * 256;
          float4 k4 = *(const float4*)(kp + u);
          s += sh_vnv[u + 0] * tanhft(k4.x + sh_qb[u + 0]);
          s += sh_vnv[u + 1] * tanhft(k4.y + sh_qb[u + 1]);
          s += sh_vnv[u + 2] * tanhft(k4.z + sh_qb[u + 2]);
          s += sh_vnv[u + 3] * tanhft(k4.w + sh_qb[u + 3]);
        }
#pragma unroll
        for (int off = 32; off > 0; off >>= 1) s += __shfl_xor(s, off, 64);
        if (lane == 0) sh_sc[tq] = (tq < len) ? s : -1e30f;
      }
      __syncthreads();
      // softmax over 128 (masked entries contribute exactly 0)
      {
        float v = (tid < 128) ? sh_sc[tid] : -1e30f;
        float mx = v;
#pragma unroll
        for (int off = 32; off > 0; off >>= 1) mx = fmaxf(mx, __shfl_xor(mx, off, 64));
        if (lane == 0) sh_r[wave] = mx;
        __syncthreads();
        mx = fmaxf(fmaxf(sh_r[0], sh_r[1]), fmaxf(sh_r[2], sh_r[3]));
        float e = (tid < 128 && tid < len) ? __expf(v - mx) : 0.f;
        float sum = e;
#pragma unroll
        for (int off = 32; off > 0; off >>= 1) sum += __shfl_xor(sum, off, 64);
        if (lane == 0) sh_r[8 + wave] = sum;
        __syncthreads();
        float inv = 1.f / (sh_r[8] + sh_r[9] + sh_r[10] + sh_r[11]);
        if (tid < 128) sh_al[tid] = e * inv;
      }
      __syncthreads();
      // context = alpha @ enc_out[b]
      {
        int d = tid * 4;
        float4 acc = make_float4(0.f, 0.f, 0.f, 0.f);
        const float* ep = eout + (size_t)b * 128 * 1024 + d;
#pragma unroll 1
        for (int tq = 0; tq < len; tq++) {
          float a = sh_al[tq];
          float4 e4 = *(const float4*)(ep + (size_t)tq * 1024);
          acc.x = fmaf(a, e4.x, acc.x); acc.y = fmaf(a, e4.y, acc.y);
          acc.z = fmaf(a, e4.z, acc.z); acc.w = fmaf(a, e4.w, acc.w);
        }
        *(float4*)(ctx + b * 1024 + d) = acc;
      }
    } else if (bid >= 32 && bid < 173 && t >= 1) {
      // projection low-K half for step t-1: logits_part = attn[0:256] @ Wproj[0:256]
      int nb = bid - 32;
      int tprev = t - 1;
      const float* apar = apart + (size_t)(tprev & 1) * 131072;
      stage<256>(at, [&](int m, int kl) -> float {
        float s = 0.f;
#pragma unroll
        for (int j = 0; j < 8; j++) s += apar[j * 16384 + m * 512 + kl];
        return s;
      });
      gemm_acc<256>(Wproj, 9000, nb * 64, 9000, 0, at, red);
      epi_to(red, plo, 9000, nb * 64, 9000);
    }
    BAR();

    // phase F: attn-vector GEMM (blocks 0..63) || projection-hi + logits write (64..204)
    if (t < 128 && bid < 64) {
      int nb = bid & 7, kb = bid >> 3;
      stage<192>(at, [&](int m, int kl) -> float {
        int kk = kb * 192 + kl;
        return (kk < 512) ? h1[m * 512 + kk] : ctx[m * 1024 + kk - 512];
      });
      gemm_acc<192>(Wal, 512, nb * 64, 512, kb * 192, at, red);
      epi_to(red, apart + (size_t)(t & 1) * 131072 + kb * 16384, 512, nb * 64, 512);
    } else if (bid >= 64 && bid < 205 && t >= 1) {
      int nb = bid - 64;
      int tprev = t - 1;
      const float* apar = apart + (size_t)(tprev & 1) * 131072;
      stage<256>(at, [&](int m, int kl) -> float {
        float s = 0.f;
#pragma unroll
        for (int j = 0; j < 8; j++) s += apar[j * 16384 + m * 512 + 256 + kl];
        return s;
      });
      gemm_acc<256>(Wproj, 9000, nb * 64, 9000, 256, at, red);
      for (int i = tid; i < 2048; i += NTHR) {
        int m = i >> 6, nn = i & 63;
        int n = nb * 64 + nn;
        if (n < 9000) {
          float s = red[m * 64 + nn] + red[2048 + m * 64 + nn] +
                    red[4096 + m * 64 + nn] + red[6144 + m * 64 + nn];
          out[((size_t)m * 128 + tprev) * 9000 + n] = s + plo[(size_t)m * 9000 + n] + bproj[n];
        }
      }
    }
    if (t < 128) BAR();
  }
#undef BAR
}

extern "C" void kernel_launch(void* const* d_in, const int* in_sizes, int n_in,
                              void* d_out, int out_size, void* d_ws, size_t ws_size,
                              hipStream_t stream) {
  (void)in_sizes; (void)n_in; (void)out_size; (void)ws_size;
  // zero barrier cells, LSTM states and attn partial buffers every call
  // (also recovers from the harness's one-time 0xAA poison of d_ws)
  hipMemsetAsync(d_ws, 0, cfg::MEMSET_BYTES, stream);
  hipLaunchKernelGGL(seq2seq_kernel, dim3(NBLKS), dim3(NTHR), 0, stream,
                     (const float*)d_in[0],   // embed_in
                     (const float*)d_in[1],   // dec_embed
                     (const int*)d_in[2],     // in_seq_len
                     (const float*)d_in[3],   // enc_fw_kernel
                     (const float*)d_in[4],   // enc_fw_bias
                     (const float*)d_in[5],   // enc_bw_kernel
                     (const float*)d_in[6],   // enc_bw_bias
                     (const float*)d_in[7],   // dec_kernel0
                     (const float*)d_in[8],   // dec_bias0
                     (const float*)d_in[9],   // dec_kernel1
                     (const float*)d_in[10],  // dec_bias1
                     (const float*)d_in[11],  // w_mem
                     (const float*)d_in[12],  // w_query
                     (const float*)d_in[13],  // b_attn
                     (const float*)d_in[14],  // v_attn
                     (const float*)d_in[15],  // g_attn
                     (const float*)d_in[16],  // w_attn_layer
                     (const float*)d_in[17],  // w_proj
                     (const float*)d_in[18],  // b_proj
                     (float*)d_out, (float*)d_ws);
}

// Round 2
// 30410.931 us; speedup vs baseline: 1.6960x; 1.6960x over previous
//
#include <hip/hip_runtime.h>
#include <stdint.h>

#define NTHR 256
#define NBLKS 512

namespace cfg {
// ws layout in FLOAT units
constexpr size_t F_CELLS = 0;                     // 1024 barriers x 512 u32 (16 lines each)
constexpr size_t F_H0    = 524288;                // [32][512]
constexpr size_t F_C0    = F_H0 + 16384;
constexpr size_t F_H1    = F_C0 + 16384;
constexpr size_t F_C1    = F_H1 + 16384;
constexpr size_t F_ATTNS = F_C1 + 16384;          // [2][32][512] attn vector (parity dbuf)
constexpr size_t F_VN    = F_ATTNS + 32768;       // [512]
constexpr size_t F_CTX   = F_VN + 512;            // [32][1024]
constexpr size_t F_P0    = F_CTX + 32768;         // [16][32][2048] gate partials
constexpr size_t F_P1    = F_P0 + 1048576;        // [16][32][2048]
constexpr size_t F_EOUT  = F_P1 + 1048576;        // [32][128][1024] encoder output (write-once)
constexpr size_t F_KEYS  = F_EOUT + 4194304;      // [32][128][512]  keys (write-once)
constexpr size_t F_TOTAL = F_KEYS + 2097152;      // ~36.2 MB
constexpr size_t MEMSET_BYTES = F_VN * 4;         // cells + states + attn_s
}

__device__ __forceinline__ float sigm(float x)   { return 1.0f / (1.0f + __expf(-x)); }
__device__ __forceinline__ float tanhft(float x) { return 1.0f - 2.0f / (1.0f + __expf(2.0f * x)); }

// ---- agent-coherent scalar access for mutable inter-block data ----
// bypasses the (non-cross-XCD-coherent) L2 and hits the device coherence point.
__device__ __forceinline__ float cload(const float* p) {
  return __hip_atomic_load(p, __ATOMIC_RELAXED, __HIP_MEMORY_SCOPE_AGENT);
}
__device__ __forceinline__ void cstore(float* p, float v) {
  __hip_atomic_store(p, v, __ATOMIC_RELAXED, __HIP_MEMORY_SCOPE_AGENT);
}

// fast grid barrier: NO cache writeback/invalidate. Relies on:
//  (a) all cross-block data moving via agent-scope atomics (cload/cstore/atomicAdd)
//  (b) __syncthreads() draining vmcnt for every wave before the arrive.
// tree arrive: 8 group cells (one cacheline each) -> root cell.
__device__ __forceinline__ void gbar_fast(unsigned* base) {
  __syncthreads();  // compiler emits s_waitcnt vmcnt(0) before s_barrier: stores drained
  if (threadIdx.x == 0) {
    unsigned* gc = base + 32 + (blockIdx.x & 7) * 32;
    unsigned v = __hip_atomic_fetch_add(gc, 1u, __ATOMIC_RELAXED, __HIP_MEMORY_SCOPE_AGENT);
    if (v == (NBLKS / 8) - 1)
      __hip_atomic_fetch_add(base, 1u, __ATOMIC_RELAXED, __HIP_MEMORY_SCOPE_AGENT);
    while (__hip_atomic_load(base, __ATOMIC_RELAXED, __HIP_MEMORY_SCOPE_AGENT) < 8u)
      __builtin_amdgcn_s_sleep(4);
  }
  __syncthreads();
}

// full barrier WITH agent fences (L2 writeback+invalidate): used exactly twice,
// to seal the write-once plain-stored buffers (eout, keys, vn) for cached readers.
__device__ __forceinline__ void gbar_full(unsigned* base) {
  __syncthreads();
  if (threadIdx.x == 0) {
    __threadfence();
    unsigned* gc = base + 32 + (blockIdx.x & 7) * 32;
    unsigned v = __hip_atomic_fetch_add(gc, 1u, __ATOMIC_RELAXED, __HIP_MEMORY_SCOPE_AGENT);
    if (v == (NBLKS / 8) - 1)
      __hip_atomic_fetch_add(base, 1u, __ATOMIC_RELAXED, __HIP_MEMORY_SCOPE_AGENT);
    while (__hip_atomic_load(base, __ATOMIC_RELAXED, __HIP_MEMORY_SCOPE_AGENT) < 8u)
      __builtin_amdgcn_s_sleep(4);
    __threadfence();
  }
  __syncthreads();
}

// stage A-tile [32][KWIN] into LDS
template<int KWIN, typename F>
__device__ __forceinline__ void stage(float* at, F&& f) {
  __syncthreads();
  constexpr int TOT = 32 * KWIN;
  for (int i = threadIdx.x; i < TOT; i += NTHR) {
    int m = i / KWIN;
    int kl = i - m * KWIN;
    at[i] = f(m, kl);
  }
  __syncthreads();
}

// each wave: 64 consecutive n-cols (lane=n), all 32 m rows, K-chunk KWIN/4,
// UNR outstanding W-row loads per batch. Leaves 4 wave-partials in red.
template<int KWIN, int UNR>
__device__ __forceinline__ void gemm_acc(const float* __restrict__ W, int ldw,
                                         int n0, int nlim, int kw0,
                                         const float* at, float* red) {
  const int wave = threadIdx.x >> 6, lane = threadIdx.x & 63;
  constexpr int KQ = KWIN / 4;
  const int klo = wave * KQ;
  const int n = n0 + lane;
  const bool nok = n < nlim;
  const float* wp = W + (size_t)(kw0 + klo) * (size_t)ldw + n;
  float acc[32];
#pragma unroll
  for (int m = 0; m < 32; m++) acc[m] = 0.f;
#pragma unroll 1
  for (int kk = 0; kk < KQ; kk += UNR) {
    float w[UNR];
#pragma unroll
    for (int j = 0; j < UNR; j++) w[j] = nok ? wp[(size_t)j * ldw] : 0.f;
    wp += (size_t)UNR * ldw;
#pragma unroll
    for (int jj = 0; jj < UNR; jj += 4) {
      const float* ap = at + klo + kk + jj;
#pragma unroll
      for (int m = 0; m < 32; m++) {
        float4 a = *(const float4*)(ap + m * KWIN);
        acc[m] = fmaf(a.x, w[jj + 0], acc[m]);
        acc[m] = fmaf(a.y, w[jj + 1], acc[m]);
        acc[m] = fmaf(a.z, w[jj + 2], acc[m]);
        acc[m] = fmaf(a.w, w[jj + 3], acc[m]);
      }
    }
  }
#pragma unroll
  for (int m = 0; m < 32; m++) red[(wave * 32 + m) * 64 + lane] = acc[m];
  __syncthreads();
}

// reduce 4 wave-partials and cstore to a [32][ldo] buffer at col n0
__device__ __forceinline__ void epi_cstore(const float* red, float* outp, int ldo, int n0) {
  for (int i = threadIdx.x; i < 2048; i += NTHR) {
    int m = i >> 6, nn = i & 63;
    float s = red[m * 64 + nn] + red[2048 + m * 64 + nn] +
              red[4096 + m * 64 + nn] + red[6144 + m * 64 + nn];
    cstore(outp + (size_t)m * ldo + n0 + nn, s);
  }
}

__global__ __launch_bounds__(NTHR, 2) void seq2seq_kernel(
    const float* __restrict__ embed_in, const float* __restrict__ dec_embed,
    const int* __restrict__ lens,
    const float* __restrict__ Wfw, const float* __restrict__ bfw,
    const float* __restrict__ Wbw, const float* __restrict__ bbw,
    const float* __restrict__ Wd0, const float* __restrict__ bd0,
    const float* __restrict__ Wd1, const float* __restrict__ bd1,
    const float* __restrict__ Wmem, const float* __restrict__ Wq,
    const float* __restrict__ battn, const float* __restrict__ vattn,
    const float* __restrict__ gattn, const float* __restrict__ Wal,
    const float* __restrict__ Wproj, const float* __restrict__ bproj,
    float* __restrict__ out, float* ws) {
  __shared__ float smem[16384];  // 64 KiB: at=[0,8192), red=[8192,16384) -> 2 blocks/CU
  float* at  = smem;
  float* red = smem + 8192;

  unsigned* cells = (unsigned*)ws;
  float* h0     = ws + cfg::F_H0;
  float* c0     = ws + cfg::F_C0;
  float* h1     = ws + cfg::F_H1;
  float* c1     = ws + cfg::F_C1;
  float* attn_s = ws + cfg::F_ATTNS;  // [2][32][512], parity stride 16384
  float* vn     = ws + cfg::F_VN;
  float* ctx    = ws + cfg::F_CTX;
  float* p0     = ws + cfg::F_P0;
  float* p1     = ws + cfg::F_P1;
  float* eout   = ws + cfg::F_EOUT;
  float* keysp  = ws + cfg::F_KEYS;

  const int bid = blockIdx.x, tid = threadIdx.x;
  const int wave = tid >> 6, lane = tid & 63;
  unsigned* cellp = cells;
#define BAR()  do { gbar_fast(cellp); cellp += 512; } while (0)
#define BARF() do { gbar_full(cellp); cellp += 512; } while (0)

  // ---------------- setup: normalized attention vector ----------------
  if (bid == 0) {
    float s = 0.f;
    for (int u = tid; u < 512; u += NTHR) { float x = vattn[u]; s = fmaf(x, x, s); }
#pragma unroll
    for (int off = 32; off > 0; off >>= 1) s += __shfl_xor(s, off, 64);
    if (lane == 0) at[64 + wave] = s;
    __syncthreads();
    float S = at[64] + at[65] + at[66] + at[67];
    float scale = gattn[0] / sqrtf(S);
    for (int u = tid; u < 512; u += NTHR) vn[u] = vattn[u] * scale;  // plain; sealed by BARF later
  }
  BAR();

  // ---------------- bidirectional encoder ----------------
  for (int t = 0; t < 128; t++) {
    // phase A: fw+bw gate GEMMs: 2dir x 32nb x 8kb = 512 blocks, KWIN=128
    {
      int dir = bid >> 8;
      int r = bid & 255;
      int nb = r & 31, kb = r >> 5;
      const float* W = dir ? Wbw : Wfw;
      const float* hs = dir ? h1 : h0;
      stage<128>(at, [&](int m, int kl) -> float {
        int kk = kb * 128 + kl;
        if (kk < 512) {
          int tt = t;
          if (dir) { int len = lens[m]; tt = (t < len) ? (len - 1 - t) : t; }
          return embed_in[((size_t)m * 128 + tt) * 512 + kk];  // read-only: plain cached
        }
        return cload(hs + m * 512 + kk - 512);
      });
      gemm_acc<128, 8>(W, 2048, nb * 64, 2048, kb * 128, at, red);
      epi_cstore(red, (dir ? p1 : p0) + (size_t)kb * 65536, 2048, nb * 64);
    }
    BAR();
    // phase B: activations + masked state update + enc_out write (128 blocks)
    if (bid < 128) {
      int dir = bid >> 6;
      int p = (bid & 63) * NTHR + tid;  // 0..16383
      int m = p >> 9, u = p & 511;
      const float* parts = dir ? p1 : p0;
      const float* bias  = dir ? bbw : bfw;
      float* hs = dir ? h1 : h0;
      float* cs = dir ? c1 : c0;
      float g4[4];
#pragma unroll
      for (int g = 0; g < 4; g++) {
        float s = bias[g * 512 + u];
#pragma unroll
        for (int j = 0; j < 8; j++) s += cload(parts + (size_t)j * 65536 + m * 2048 + g * 512 + u);
        g4[g] = s;
      }
      int len = lens[m];
      bool valid = t < len;
      float co = cload(cs + m * 512 + u);
      float cn = sigm(g4[2] + 1.f) * co + sigm(g4[0]) * tanhft(g4[1]);
      float hn = sigm(g4[3]) * tanhft(cn);
      if (valid) { cstore(cs + m * 512 + u, cn); cstore(hs + m * 512 + u, hn); }
      int tpos = dir ? (valid ? (len - 1 - t) : t) : t;
      eout[((size_t)m * 128 + tpos) * 1024 + dir * 512 + u] = valid ? hn : 0.f;  // plain (sealed by BARF)
    }
    BAR();
  }

  BARF();  // seal eout (+vn) for cached readers

  // ---------------- keys = enc_out @ w_mem  (M=4096, N=512, K=1024) ----------------
  {
#pragma unroll 1
    for (int task = bid; task < 1024; task += NBLKS) {
      int mt = task >> 3, nb = task & 7;
      int n0 = nb * 64;
      const float* arow = eout + (size_t)mt * 32 * 1024;
      float acc[32];
#pragma unroll
      for (int m = 0; m < 32; m++) acc[m] = 0.f;
      const int n = n0 + lane;
#pragma unroll 1
      for (int c = 0; c < 4; c++) {
        stage<256>(at, [&](int m, int kl) -> float {
          return arow[(size_t)m * 1024 + c * 256 + kl];
        });
        const int klo = wave * 64;
        const float* wp = Wmem + (size_t)(c * 256 + klo) * 512 + n;
#pragma unroll 1
        for (int kk = 0; kk < 64; kk += 8) {
          float w[8];
#pragma unroll
          for (int j = 0; j < 8; j++) w[j] = wp[(size_t)j * 512];
          wp += (size_t)8 * 512;
#pragma unroll
          for (int jj = 0; jj < 8; jj += 4) {
            const float* ap = at + klo + kk + jj;
#pragma unroll
            for (int m = 0; m < 32; m++) {
              float4 a = *(const float4*)(ap + m * 256);
              acc[m] = fmaf(a.x, w[jj + 0], acc[m]); acc[m] = fmaf(a.y, w[jj + 1], acc[m]);
              acc[m] = fmaf(a.z, w[jj + 2], acc[m]); acc[m] = fmaf(a.w, w[jj + 3], acc[m]);
            }
          }
        }
      }
      __syncthreads();
#pragma unroll
      for (int m = 0; m < 32; m++) red[(wave * 32 + m) * 64 + lane] = acc[m];
      __syncthreads();
      for (int i = tid; i < 2048; i += NTHR) {
        int m = i >> 6, nn = i & 63;
        float s = red[m * 64 + nn] + red[2048 + m * 64 + nn] +
                  red[4096 + m * 64 + nn] + red[6144 + m * 64 + nn];
        keysp[(size_t)mt * 32 * 512 + (size_t)m * 512 + n0 + nn] = s;  // plain (sealed by BARF)
      }
    }
  }
  BARF();  // seal keys

  // ---------------- decoder loop (t==128: trailing projection only) ----------------
  for (int t = 0; t <= 128; t++) {
    if (t < 128) {
      // phase A: gates0 GEMM, K=1536 = x(512) | attn(512) | h0(512); 32nb x 16kb, KWIN=96
      {
        int nb = bid & 31, kb = bid >> 5;
        const float* asrc = attn_s + (size_t)((t + 1) & 1) * 16384;  // attn(t-1)
        stage<96>(at, [&](int m, int kl) -> float {
          int kk = kb * 96 + kl;
          if (kk < 512) return dec_embed[((size_t)m * 128 + t) * 512 + kk];
          if (kk < 1024) return cload(asrc + m * 512 + kk - 512);
          return cload(h0 + m * 512 + kk - 1024);
        });
        gemm_acc<96, 8>(Wd0, 2048, nb * 64, 2048, kb * 96, at, red);
        epi_cstore(red, p0 + (size_t)kb * 65536, 2048, nb * 64);
      }
      BAR();
      // phase B: act0 (64 blocks) + zero attn_s[t&1] (blocks 64..71)
      if (bid < 64) {
        int p = bid * NTHR + tid;
        int m = p >> 9, u = p & 511;
        float g4[4];
#pragma unroll
        for (int g = 0; g < 4; g++) {
          float s = bd0[g * 512 + u];
#pragma unroll
          for (int j = 0; j < 16; j++) s += cload(p0 + (size_t)j * 65536 + m * 2048 + g * 512 + u);
          g4[g] = s;
        }
        float co = cload(c0 + m * 512 + u);
        float cn = sigm(g4[2] + 1.f) * co + sigm(g4[0]) * tanhft(g4[1]);
        float hn = sigm(g4[3]) * tanhft(cn);
        cstore(c0 + m * 512 + u, cn);
        cstore(h0 + m * 512 + u, hn);
      } else if (bid < 72) {
        float* az = attn_s + (size_t)(t & 1) * 16384 + (size_t)(bid - 64) * 2048;
        for (int i = tid; i < 2048; i += NTHR) cstore(az + i, 0.f);
      }
      BAR();
      // phase C: gates1 GEMM, K=1024 = h0new | h1old; 32nb x 16kb, KWIN=64
      {
        int nb = bid & 31, kb = bid >> 5;
        stage<64>(at, [&](int m, int kl) -> float {
          int kk = kb * 64 + kl;
          return (kk < 512) ? cload(h0 + m * 512 + kk) : cload(h1 + m * 512 + kk - 512);
        });
        gemm_acc<64, 8>(Wd1, 2048, nb * 64, 2048, kb * 64, at, red);
        epi_cstore(red, p1 + (size_t)kb * 65536, 2048, nb * 64);
      }
      BAR();
    }

    // phase E: attention (blocks 0..31) || full-K projection of step t-1 (blocks 32..172)
    if (t < 128 && bid < 32) {
      int b = bid;
      int len = lens[b];
      float* sh_h1v = at;          // 512
      float* sh_qb  = at + 512;    // 512
      float* sh_vnv = at + 1024;   // 512
      float* sh_sc  = at + 1536;   // 128
      float* sh_al  = at + 1664;   // 128
      float* sh_r   = at + 1792;   // 16
      float* redq   = at + 2048;   // 2048
      // act1 for row b (sole writer) + stage vn
#pragma unroll 1
      for (int u = tid; u < 512; u += NTHR) {
        float g4[4];
#pragma unroll
        for (int g = 0; g < 4; g++) {
          float s = bd1[g * 512 + u];
#pragma unroll
          for (int j = 0; j < 16; j++) s += cload(p1 + (size_t)j * 65536 + b * 2048 + g * 512 + u);
          g4[g] = s;
        }
        float co = cload(c1 + b * 512 + u);
        float cn = sigm(g4[2] + 1.f) * co + sigm(g4[0]) * tanhft(g4[1]);
        float hn = sigm(g4[3]) * tanhft(cn);
        cstore(c1 + b * 512 + u, cn);
        cstore(h1 + b * 512 + u, hn);
        sh_h1v[u] = hn;
        sh_vnv[u] = vn[u];
      }
      __syncthreads();
      // q = h1n @ w_query
      {
        float4 qa = make_float4(0.f, 0.f, 0.f, 0.f), qb4 = make_float4(0.f, 0.f, 0.f, 0.f);
        const int ua = lane * 4, ub = 256 + lane * 4;
        const float* wqp = Wq + (size_t)(wave * 128) * 512;
#pragma unroll 1
        for (int kk = 0; kk < 128; kk++) {
          float h = sh_h1v[wave * 128 + kk];
          float4 wa = *(const float4*)(wqp + (size_t)kk * 512 + ua);
          float4 wb = *(const float4*)(wqp + (size_t)kk * 512 + ub);
          qa.x = fmaf(h, wa.x, qa.x); qa.y = fmaf(h, wa.y, qa.y);
          qa.z = fmaf(h, wa.z, qa.z); qa.w = fmaf(h, wa.w, qa.w);
          qb4.x = fmaf(h, wb.x, qb4.x); qb4.y = fmaf(h, wb.y, qb4.y);
          qb4.z = fmaf(h, wb.z, qb4.z); qb4.w = fmaf(h, wb.w, qb4.w);
        }
        *(float4*)(redq + wave * 512 + ua) = qa;
        *(float4*)(redq + wave * 512 + ub) = qb4;
      }
      __syncthreads();
      for (int u = tid; u < 512; u += NTHR)
        sh_qb[u] = redq[u] + redq[512 + u] + redq[1024 + u] + redq[1536 + u] + battn[u];
      __syncthreads();
      // scores
#pragma unroll 1
      for (int tt = 0; tt < 32; tt++) {
        int tq = wave * 32 + tt;
        const float* kp = keysp + ((size_t)b * 128 + tq) * 512;
        float s = 0.f;
#pragma unroll
        for (int hh = 0; hh < 2; hh++) {
          int u = lane * 4 + hh * 256;
          float4 k4 = *(const float4*)(kp + u);
          s += sh_vnv[u + 0] * tanhft(k4.x + sh_qb[u + 0]);
          s += sh_vnv[u + 1] * tanhft(k4.y + sh_qb[u + 1]);
          s += sh_vnv[u + 2] * tanhft(k4.z + sh_qb[u + 2]);
          s += sh_vnv[u + 3] * tanhft(k4.w + sh_qb[u + 3]);
        }
#pragma unroll
        for (int off = 32; off > 0; off >>= 1) s += __shfl_xor(s, off, 64);
        if (lane == 0) sh_sc[tq] = (tq < len) ? s : -1e30f;
      }
      __syncthreads();
      // softmax over 128
      {
        float v = (tid < 128) ? sh_sc[tid] : -1e30f;
        float mx = v;
#pragma unroll
        for (int off = 32; off > 0; off >>= 1) mx = fmaxf(mx, __shfl_xor(mx, off, 64));
        if (lane == 0) sh_r[wave] = mx;
        __syncthreads();
        mx = fmaxf(fmaxf(sh_r[0], sh_r[1]), fmaxf(sh_r[2], sh_r[3]));
        float e = (tid < 128 && tid < len) ? __expf(v - mx) : 0.f;
        float sum = e;
#pragma unroll
        for (int off = 32; off > 0; off >>= 1) sum += __shfl_xor(sum, off, 64);
        if (lane == 0) sh_r[8 + wave] = sum;
        __syncthreads();
        float inv = 1.f / (sh_r[8] + sh_r[9] + sh_r[10] + sh_r[11]);
        if (tid < 128) sh_al[tid] = e * inv;
      }
      __syncthreads();
      // context = alpha @ enc_out[b]
      {
        int d = tid * 4;
        float4 acc = make_float4(0.f, 0.f, 0.f, 0.f);
        const float* ep = eout + (size_t)b * 128 * 1024 + d;
#pragma unroll 1
        for (int tq = 0; tq < len; tq++) {
          float a = sh_al[tq];
          float4 e4 = *(const float4*)(ep + (size_t)tq * 1024);
          acc.x = fmaf(a, e4.x, acc.x); acc.y = fmaf(a, e4.y, acc.y);
          acc.z = fmaf(a, e4.z, acc.z); acc.w = fmaf(a, e4.w, acc.w);
        }
        cstore(ctx + b * 1024 + d + 0, acc.x);
        cstore(ctx + b * 1024 + d + 1, acc.y);
        cstore(ctx + b * 1024 + d + 2, acc.z);
        cstore(ctx + b * 1024 + d + 3, acc.w);
      }
    } else if (bid >= 32 && bid < 173 && t >= 1) {
      // projection for step t-1: logits = attn(t-1) @ Wproj + bproj, full K=512 per block
      int nb = bid - 32;
      int n0 = nb * 64;
      int tprev = t - 1;
      const float* asrc = attn_s + (size_t)((t + 1) & 1) * 16384;  // attn(t-1)
      const int n = n0 + lane;
      const bool nok = n < 9000;
      float acc[32];
#pragma unroll
      for (int m = 0; m < 32; m++) acc[m] = 0.f;
#pragma unroll 1
      for (int c = 0; c < 2; c++) {
        stage<256>(at, [&](int m, int kl) -> float {
          return cload(asrc + m * 512 + c * 256 + kl);
        });
        const int klo = wave * 64;
        const float* wp = Wproj + (size_t)(c * 256 + klo) * 9000 + n;
#pragma unroll 1
        for (int kk = 0; kk < 64; kk += 16) {
          float w[16];
#pragma unroll
          for (int j = 0; j < 16; j++) w[j] = nok ? wp[(size_t)j * 9000] : 0.f;
          wp += (size_t)16 * 9000;
#pragma unroll
          for (int jj = 0; jj < 16; jj += 4) {
            const float* ap = at + klo + kk + jj;
#pragma unroll
            for (int m = 0; m < 32; m++) {
              float4 a = *(const float4*)(ap + m * 256);
              acc[m] = fmaf(a.x, w[jj + 0], acc[m]); acc[m] = fmaf(a.y, w[jj + 1], acc[m]);
              acc[m] = fmaf(a.z, w[jj + 2], acc[m]); acc[m] = fmaf(a.w, w[jj + 3], acc[m]);
            }
          }
        }
      }
      __syncthreads();
#pragma unroll
      for (int m = 0; m < 32; m++) red[(wave * 32 + m) * 64 + lane] = acc[m];
      __syncthreads();
      for (int i = tid; i < 2048; i += NTHR) {
        int m = i >> 6, nn = i & 63;
        int nc = n0 + nn;
        if (nc < 9000) {
          float s = red[m * 64 + nn] + red[2048 + m * 64 + nn] +
                    red[4096 + m * 64 + nn] + red[6144 + m * 64 + nn];
          out[((size_t)m * 128 + tprev) * 9000 + nc] = s + bproj[nc];  // plain: host-consumed
        }
      }
    }
    BAR();

    // phase F: attn-vector GEMM: attn(t) = (h1|ctx) @ Wal; 8nb x 8kb = 64 blocks, KWIN=192
    if (t < 128) {
      if (bid < 64) {
        int nb = bid & 7, kb = bid >> 3;
        stage<192>(at, [&](int m, int kl) -> float {
          int kk = kb * 192 + kl;
          return (kk < 512) ? cload(h1 + m * 512 + kk) : cload(ctx + m * 1024 + kk - 512);
        });
        gemm_acc<192, 8>(Wal, 512, nb * 64, 512, kb * 192, at, red);
        float* adst = attn_s + (size_t)(t & 1) * 16384;
        for (int i = tid; i < 2048; i += NTHR) {
          int m = i >> 6, nn = i & 63;
          float s = red[m * 64 + nn] + red[2048 + m * 64 + nn] +
                    red[4096 + m * 64 + nn] + red[6144 + m * 64 + nn];
          atomicAdd(adst + (size_t)m * 512 + nb * 64 + nn, s);
        }
      }
      BAR();
    }
  }
#undef BAR
#undef BARF
}

extern "C" void kernel_launch(void* const* d_in, const int* in_sizes, int n_in,
                              void* d_out, int out_size, void* d_ws, size_t ws_size,
                              hipStream_t stream) {
  (void)in_sizes; (void)n_in; (void)out_size; (void)ws_size;
  // zero barrier cells, LSTM states, attn vector buffers every call
  hipMemsetAsync(d_ws, 0, cfg::MEMSET_BYTES, stream);
  hipLaunchKernelGGL(seq2seq_kernel, dim3(NBLKS), dim3(NTHR), 0, stream,
                     (const float*)d_in[0],   // embed_in
                     (const float*)d_in[1],   // dec_embed
                     (const int*)d_in[2],     // in_seq_len
                     (const float*)d_in[3],   // enc_fw_kernel
                     (const float*)d_in[4],   // enc_fw_bias
                     (const float*)d_in[5],   // enc_bw_kernel
                     (const float*)d_in[6],   // enc_bw_bias
                     (const float*)d_in[7],   // dec_kernel0
                     (const float*)d_in[8],   // dec_bias0
                     (const float*)d_in[9],   // dec_kernel1
                     (const float*)d_in[10],  // dec_bias1
                     (const float*)d_in[11],  // w_mem
                     (const float*)d_in[12],  // w_query
                     (const float*)d_in[13],  // b_attn
                     (const float*)d_in[14],  // v_attn
                     (const float*)d_in[15],  // g_attn
                     (const float*)d_in[16],  // w_attn_layer
                     (const float*)d_in[17],  // w_proj
                     (const float*)d_in[18],  // b_proj
                     (float*)d_out, (float*)d_ws);
}